// Round 4
// baseline (209.296 us; speedup 1.0000x reference)
//
#include <hip/hip_runtime.h>
#include <math.h>

typedef unsigned int uint;

constexpr int N_USERS  = 50000;
constexpr int N_ENT    = 100000;
constexpr int D        = 64;
constexpr int N_FAC    = 4;
constexpr int N_CLS    = 8;
constexpr int N_REL    = 16;
constexpr int N_EDGES  = 1000000;
constexpr int N_INTER  = 500000;

// bucket-sort geometry
constexpr int BSH      = 7;                              // 128 segments per bucket
constexpr int SPB      = 1 << BSH;                       // 128
constexpr int NBKT_E   = (N_ENT   + SPB - 1) / SPB;      // 782
constexpr int NBKT_U   = (N_USERS + SPB - 1) / SPB;      // 391
constexpr int CHUNK    = 4096;                           // edges per sort block
constexpr int NB_E     = (N_EDGES + CHUNK - 1) / CHUNK;  // 245
constexpr int NB_U     = (N_INTER + CHUNK - 1) / CHUNK;  // 123
constexpr int EBUF_CAP = 3072;                           // max bucket size (mean ~1280)

constexpr int E_ROWS   = N_ENT + 1;                      // incl. zero row

// ---- f16x2 helpers (packed two f16 in one uint) ----
typedef _Float16 h2_t __attribute__((ext_vector_type(2)));
union U32H2 { uint u; h2_t h; };

__device__ inline float h_lo(uint v) { U32H2 x; x.u = v; return (float)x.h.x; }
__device__ inline float h_hi(uint v) { U32H2 x; x.u = v; return (float)x.h.y; }
__device__ inline uint packh(float a, float b) {
    auto r = __builtin_amdgcn_cvt_pkrtz(a, b);   // v_cvt_pkrtz_f16_f32, single inst
    union { decltype(r) h; uint u; } x;
    x.h = r;
    return x.u;
}

__device__ inline int wscan64_incl(int x, int lane) {
#pragma unroll
    for (int off = 1; off < 64; off <<= 1) {
        int v = __shfl_up(x, off, 64);
        if (lane >= off) x += v;
    }
    return x;
}

// 256-thread block scan (inclusive) of per-thread values
__device__ inline int block_scan_incl(int x, int* wsum) {
    int lane = threadIdx.x & 63, wv = threadIdx.x >> 6;
#pragma unroll
    for (int off = 1; off < 64; off <<= 1) {
        int v = __shfl_up(x, off, 64);
        if (lane >= off) x += v;
    }
    if (lane == 63) wsum[wv] = x;
    __syncthreads();
    if (wv == 0 && lane < 16) {
        int s = wsum[lane];
#pragma unroll
        for (int off = 1; off < 16; off <<= 1) {
            int v = __shfl_up(s, off, 64);
            if (lane >= off) s += v;
        }
        wsum[lane] = s;
    }
    __syncthreads();
    if (wv > 0) x += wsum[wv - 1];
    return x;
}

// ---- fused: f32 -> f16 entity table convert (blocks 0..N-2)
//      + dw/loss/rel-f16-table + election-counter zero (last block) ----
__global__ void k_cvt_dw(const float2* __restrict__ in, uint* __restrict__ out,
                         int n_src, int n_out,
                         const float* __restrict__ datt,
                         const float* __restrict__ rel,
                         float* __restrict__ dw,
                         float* __restrict__ loss_out,
                         uint4* __restrict__ relh4,
                         int* __restrict__ done_ctr) {
    __shared__ float p[N_FAC][N_REL];
    __shared__ float nrm[N_FAC];
    __shared__ float sc[N_FAC][N_FAC];
    int t = threadIdx.x;
    if (blockIdx.x == gridDim.x - 1) {
        if (t == 0) *done_ctr = 0;
        // f16 rel table (128 slots)
        for (int s = t; s < N_REL * 8; s += 256) {
            int r = s >> 3, kk = s & 7;
            const float* rp = rel + r * 64 + kk * 8;
            relh4[s] = make_uint4(packh(rp[0], rp[1]), packh(rp[2], rp[3]),
                                  packh(rp[4], rp[5]), packh(rp[6], rp[7]));
        }
        if (t < N_FAC) {
            float m = -1e30f;
            for (int r = 0; r < N_REL; ++r) m = fmaxf(m, datt[t * N_REL + r]);
            float tmp[N_REL]; float s = 0.f;
            for (int r = 0; r < N_REL; ++r) { tmp[r] = expf(datt[t * N_REL + r] - m); s += tmp[r]; }
            for (int r = 0; r < N_REL; ++r) p[t][r] = tmp[r] / s;
            float ss = 0.f;
            for (int r = 0; r < N_REL; ++r) { float v = datt[t * N_REL + r]; ss += v * v; }
            nrm[t] = fmaxf(sqrtf(ss), 1e-12f);
        }
        __syncthreads();
        if (t < D) {
            for (int f = 0; f < N_FAC; ++f) {
                float acc = 0.f;
                for (int r = 0; r < N_REL; ++r) acc += p[f][r] * rel[r * D + t];
                dw[f * D + t] = acc;
            }
        }
        if (t < N_FAC * N_FAC) {
            int i = t >> 2, j = t & 3;
            float s = 0.f;
            for (int r = 0; r < N_REL; ++r) s += datt[i * N_REL + r] * datt[j * N_REL + r];
            s /= nrm[i] * nrm[j];
            sc[i][j] = expf(s * 5.0f);   // exp(s / 0.2)
        }
        __syncthreads();
        if (t == 0) {
            float loss = 0.f;
            for (int i = 0; i < N_FAC; ++i) {
                float rowsum = 0.f;
                for (int j = 0; j < N_FAC; ++j) rowsum += sc[i][j];
                loss += logf(sc[i][i] / rowsum);
            }
            *loss_out = -loss;
        }
        return;
    }
    int nb = gridDim.x - 1;
    for (int i = blockIdx.x * 256 + t; i < n_out; i += nb * 256) {
        if (i < n_src) {
            float2 v = in[i];
            out[i] = packh(v.x, v.y);
        } else {
            out[i] = 0u;
        }
    }
}

// ---- P1: per-block LDS counting sort -> linear staging (all writes coalesced) ----
__global__ void k_sort(const int* __restrict__ headE, const int* __restrict__ tailE,
                       const int* __restrict__ etype,
                       const int* __restrict__ iu, const int* __restrict__ ii,
                       const int* __restrict__ icls, const float* __restrict__ ival,
                       uint2* __restrict__ stagE, int* __restrict__ GE, int* __restrict__ RE,
                       uint2* __restrict__ stagU, int* __restrict__ GU, int* __restrict__ RU) {
    __shared__ int hist[NBKT_E];
    __shared__ int soff[NBKT_E + 1];
    __shared__ int cursor[NBKT_E];
    __shared__ int wsum[16];
    __shared__ uint2 sorted[CHUNK];
    int bid = blockIdx.x;
    bool isE = bid < NB_E;
    int blk  = isE ? bid : bid - NB_E;
    int n    = isE ? N_EDGES : N_INTER;
    int nbkt = isE ? NBKT_E : NBKT_U;
    int base = blk * CHUNK;
    int end  = min(base + CHUNK, n);
    int cblk = end - base;

    for (int b = threadIdx.x; b < nbkt; b += 256) hist[b] = 0;
    __syncthreads();

    // load 16 edges/thread into registers (static indexing), histogram buckets
    uint2 ent[16]; int ebk[16];
#pragma unroll
    for (int j = 0; j < 16; ++j) {
        int i = base + threadIdx.x + j * 256;
        ebk[j] = -1;
        if (i < end) {
            uint x, y; int b;
            if (isE) {
                int h = headE[i];
                x = (uint)h; y = (uint)((tailE[i] << 4) | etype[i]); b = h >> BSH;
            } else {
                int u = iu[i];
                x = (uint)((u << 15) | ii[i]);
                y = (__float_as_uint(ival[i]) & ~7u) | (uint)icls[i];
                b = u >> BSH;
            }
            ent[j] = make_uint2(x, y); ebk[j] = b;
            atomicAdd(&hist[b], 1);
        }
    }
    __syncthreads();

    // block scan over nbkt bins: thread t owns bins [t*4, t*4+4)
    int b0 = threadIdx.x * 4;
    int lsum[4]; int mysum = 0;
#pragma unroll
    for (int j = 0; j < 4; ++j) {
        int b = b0 + j;
        int v = (b < nbkt) ? hist[b] : 0;
        lsum[j] = mysum; mysum += v;
    }
    int excl = block_scan_incl(mysum, wsum) - mysum;
#pragma unroll
    for (int j = 0; j < 4; ++j) {
        int b = b0 + j;
        if (b < nbkt) soff[b] = excl + lsum[j];
    }
    if (threadIdx.x == 0) soff[nbkt] = cblk;
    __syncthreads();
    for (int b = threadIdx.x; b < nbkt; b += 256) cursor[b] = soff[b];
    __syncthreads();

    // LDS scatter into sorted order
#pragma unroll
    for (int j = 0; j < 16; ++j) {
        if (ebk[j] >= 0) {
            int p = atomicAdd(&cursor[ebk[j]], 1);
            sorted[p] = ent[j];
        }
    }
    __syncthreads();

    // coalesced writes: staging chunk + hist row + rowscan row
    uint2* stag = isE ? stagE : stagU;
    int* G = isE ? GE : GU;
    int* R = isE ? RE : RU;
    for (int i = threadIdx.x; i < cblk; i += 256) stag[blk * CHUNK + i] = sorted[i];
    for (int b = threadIdx.x; b < nbkt; b += 256) G[blk * nbkt + b] = hist[b];
    for (int b = threadIdx.x; b <= nbkt; b += 256) R[blk * (nbkt + 1) + b] = soff[b];
}

// ---- P2b helper: scan bucket totals -> bucket bases ----
__device__ inline void scan_tot(const int* __restrict__ tot, int* __restrict__ base,
                                int nbkt, int l, int* __restrict__ off_last, int nseg) {
    int carry = 0;
    for (int b = 0; b < nbkt; b += 64) {
        int x = (b + l < nbkt) ? tot[b + l] : 0;
        int incl = wscan64_incl(x, l);
        if (b + l < nbkt) base[b + l] = carry + incl - x;
        carry += __shfl(incl, 63, 64);
    }
    if (l == 0) {
        base[nbkt] = carry;
        off_last[nseg] = carry;
        off_last[nseg + 1] = carry;   // zero-row segment (entity) / unused (user)
    }
}

// ---- P2: per-bucket exclusive scan over blocks; LAST block (device-atomic
// election) scans the bucket totals -> bases. Fuses old bscanA + bscanB. ----
__global__ void k_bscan(int* __restrict__ GE, int* __restrict__ totE,
                        int* __restrict__ GU, int* __restrict__ totU,
                        int* __restrict__ baseE, int* __restrict__ baseU,
                        int* __restrict__ eoff, int* __restrict__ uoff,
                        int* __restrict__ done_ctr) {
    int bid = blockIdx.x;
    bool isE = bid < NBKT_E;
    int bkt  = isE ? bid : bid - NBKT_E;
    int NB   = isE ? NB_E : NB_U;
    int nbkt = isE ? NBKT_E : NBKT_U;
    int* G   = isE ? GE : GU;
    int* tot = isE ? totE : totU;
    int l = threadIdx.x;
    int carry = 0;
    for (int base = 0; base < NB; base += 64) {
        int x = (base + l < NB) ? G[(base + l) * nbkt + bkt] : 0;
        int incl = wscan64_incl(x, l);
        if (base + l < NB) G[(base + l) * nbkt + bkt] = carry + incl - x;
        carry += __shfl(incl, 63, 64);
    }
    if (l == 0) tot[bkt] = carry;
    // election: the last block to finish runs the total-scans
    __threadfence();
    __shared__ int amlast;
    if (l == 0) amlast = (atomicAdd(done_ctr, 1) == NBKT_E + NBKT_U - 1);
    __syncthreads();
    if (amlast) {
        __threadfence();
        scan_tot(totE, baseE, NBKT_E, l, eoff, N_ENT);
        scan_tot(totU, baseU, NBKT_U, l, uoff, N_USERS);
    }
}

// ---- P3: per-bucket finalize: gather runs (scattered READS), seg sort, place ----
__global__ void k_final(const uint2* __restrict__ stagE, const int* __restrict__ GE,
                        const int* __restrict__ RE, const int* __restrict__ baseE,
                        const uint2* __restrict__ stagU, const int* __restrict__ GU,
                        const int* __restrict__ RU, const int* __restrict__ baseU,
                        int* __restrict__ eoff, int* __restrict__ uoff,
                        int* __restrict__ epay, int2* __restrict__ ipv) {
    __shared__ uint2 ebuf[EBUF_CAP];
    __shared__ int cnt[SPB], soff[SPB], cur[SPB];
    int bid = blockIdx.x;
    bool isE = bid < NBKT_E;
    int bkt = bid < NBKT_E ? bid : bid - NBKT_E;
    const uint2* stag = isE ? stagE : stagU;
    const int* G  = isE ? GE : GU;
    const int* R  = isE ? RE : RU;
    const int* bb = isE ? baseE : baseU;
    int* off      = isE ? eoff : uoff;
    int NB   = isE ? NB_E : NB_U;
    int nbkt = isE ? NBKT_E : NBKT_U;
    int nseg = isE ? N_ENT : N_USERS;
    int r0 = bb[bkt], r1 = bb[bkt + 1];
    int bsz = r1 - r0;
    int t = threadIdx.x;
    if (t < SPB) cnt[t] = 0;
    // phase A: gather each block's run into LDS at its bucket-relative offset
    for (int blk = t; blk < NB; blk += 256) {
        int rs  = R[blk * (nbkt + 1) + bkt];
        int re  = R[blk * (nbkt + 1) + bkt + 1];
        int dst = G[blk * nbkt + bkt];
        for (int j = rs; j < re; ++j) {
            int d = dst + (j - rs);
            if (d < EBUF_CAP) ebuf[d] = stag[blk * CHUNK + j];
        }
    }
    __syncthreads();
    // phase B: histogram over 128 segments
    for (int i = t; i < bsz; i += 256) {
        uint2 e = ebuf[i];
        int s = (int)(isE ? e.x : (e.x >> 15)) & (SPB - 1);
        atomicAdd(&cnt[s], 1);
    }
    __syncthreads();
    // phase C: scan 128 segments
    if (t < 64) {
        int a0 = cnt[2 * t], a1 = cnt[2 * t + 1];
        int incl = wscan64_incl(a0 + a1, t);
        int excl = incl - (a0 + a1);
        soff[2 * t] = excl;
        soff[2 * t + 1] = excl + a0;
    }
    __syncthreads();
    if (t < SPB) {
        cur[t] = soff[t];
        int seg = bkt * SPB + t;
        if (seg < nseg) off[seg] = r0 + soff[t];
    }
    __syncthreads();
    // phase D: scatter to final CSR (writes land in this bucket's ~10 KB window)
    for (int i = t; i < bsz; i += 256) {
        uint2 e = ebuf[i];
        int s = (int)(isE ? e.x : (e.x >> 15)) & (SPB - 1);
        int pos = r0 + atomicAdd(&cur[s], 1);
        if (isE) {
            epay[pos] = (int)e.y;
        } else {
            int item = (int)(e.x & 0x7FFF), cls = (int)(e.y & 7u);
            ipv[pos] = make_int2((item << 3) | cls, (int)(e.y & ~7u));
        }
    }
}

// ---- merged hop with FUSED user attention.
// rows [0, N_ENT] = entity (incl. zero row N_ENT), rest = user.
// 8 lanes per row, 8 dims per lane (uint4 f16x8 gathers).
// Depth-8 register gather pipeline; f16 rel table (one uint4 load/edge).
// User branch computes its own att4/att8 in-register (latent/cls L1-resident,
// 8-lane butterfly reduce) - no separate k_user_att dispatches.
// MODE 0: att from f32 user_emb; write packed states.
// MODE 1: att from f16 uA state; out = base + own_state + v.
template<int MODE>
__global__ __launch_bounds__(256)
void k_hop(const uint4* __restrict__ etab,      // gather table (f16), E_ROWS rows
           const float4* __restrict__ entbase,  // entity_emb (MODE 1)
           const float4* __restrict__ usrbase,  // user_emb f32 (att MODE 0; base MODE 1)
           const uint4* __restrict__ ustate_in, // uA f16 (att + own, MODE 1)
           const uint4* __restrict__ relh4,     // f16 rel table [16][8]
           const int* __restrict__ eoff,
           const int* __restrict__ epay,
           const int* __restrict__ uoff,
           const int2* __restrict__ ipv,
           const float4* __restrict__ latent4,  // f32 [4][16]
           const float4* __restrict__ cls4,     // f32 [8][16]
           const float4* __restrict__ dw4,      // f32 [4][16]
           uint4* __restrict__ stateE_out,
           uint4* __restrict__ stateU_out,
           float4* __restrict__ outE,
           float4* __restrict__ outU) {
    int gid = blockIdx.x * 256 + threadIdx.x;
    int gw = gid >> 3;
    int k = threadIdx.x & 7;
    if (gw >= E_ROWS + N_USERS) return;
    bool isEnt = gw < E_ROWS;
    float a0 = 0.f, a1 = 0.f, a2 = 0.f, a3 = 0.f;
    float a4 = 0.f, a5 = 0.f, a6 = 0.f, a7 = 0.f;

    if (isEnt) {
        int w = gw;
        int beg = eoff[w], end = eoff[w + 1];
        int nE = end - beg;
        const int* pp = epay + beg;
        int pc[8];
#pragma unroll
        for (int q = 0; q < 8; ++q) pc[q] = pp[q];            // pad-safe overread
        for (int bse = 0; bse < nE; bse += 8) {
            int c = nE - bse;
            int pn[8];
#pragma unroll
            for (int q = 0; q < 8; ++q) pn[q] = pp[bse + 8 + q];  // prefetch next
            uint4 ev[8], rl[8];
#pragma unroll
            for (int q = 0; q < 8; ++q) {
                int p = (q < c) ? pc[q] : (N_ENT << 4);       // invalid -> zero row
                ev[q] = etab[(((size_t)(p >> 4)) << 3) + k];
                rl[q] = relh4[((p & 15) << 3) + k];
            }
#pragma unroll
            for (int q = 0; q < 8; ++q) {
                a0 = fmaf(h_lo(ev[q].x), h_lo(rl[q].x), a0);
                a1 = fmaf(h_hi(ev[q].x), h_hi(rl[q].x), a1);
                a2 = fmaf(h_lo(ev[q].y), h_lo(rl[q].y), a2);
                a3 = fmaf(h_hi(ev[q].y), h_hi(rl[q].y), a3);
                a4 = fmaf(h_lo(ev[q].z), h_lo(rl[q].z), a4);
                a5 = fmaf(h_hi(ev[q].z), h_hi(rl[q].z), a5);
                a6 = fmaf(h_lo(ev[q].w), h_lo(rl[q].w), a6);
                a7 = fmaf(h_hi(ev[q].w), h_hi(rl[q].w), a7);
            }
#pragma unroll
            for (int q = 0; q < 8; ++q) pc[q] = pn[q];
        }
        float ss = a0*a0 + a1*a1 + a2*a2 + a3*a3 + a4*a4 + a5*a5 + a6*a6 + a7*a7;
#pragma unroll
        for (int m = 1; m < 8; m <<= 1) ss += __shfl_xor(ss, m, 8);
        float s = 1.0f / fmaxf(sqrtf(ss), 1e-12f);
        float v0 = a0*s, v1 = a1*s, v2 = a2*s, v3 = a3*s;
        float v4 = a4*s, v5 = a5*s, v6 = a6*s, v7 = a7*s;
        if (MODE == 0) {
            stateE_out[((size_t)w << 3) + k] =
                make_uint4(packh(v0, v1), packh(v2, v3), packh(v4, v5), packh(v6, v7));
        } else if (w < N_ENT) {
            size_t b = ((size_t)w << 4) + (k << 1);
            float4 b0 = entbase[b], b1 = entbase[b + 1];
            uint4 own = etab[((size_t)w << 3) + k];
            float4 o0 = make_float4(b0.x + h_lo(own.x) + v0, b0.y + h_hi(own.x) + v1,
                                    b0.z + h_lo(own.y) + v2, b0.w + h_hi(own.y) + v3);
            float4 o1 = make_float4(b1.x + h_lo(own.z) + v4, b1.y + h_hi(own.z) + v5,
                                    b1.z + h_lo(own.w) + v6, b1.w + h_hi(own.w) + v7);
            outE[b] = o0; outE[b + 1] = o1;
        }
    } else {
        int w = gw - E_ROWS;
        int beg = uoff[w], end = uoff[w + 1];
        int nE = end - beg;
        const int2* pv = ipv + beg;

        // ---- fused attention: own row dims 8k..8k+7 ----
        float u0, u1, u2, u3, u4, u5, u6, u7;
        uint4 own;
        if (MODE == 0) {
            size_t bb = ((size_t)w << 4) + (k << 1);
            float4 x0 = usrbase[bb], x1 = usrbase[bb + 1];
            u0 = x0.x; u1 = x0.y; u2 = x0.z; u3 = x0.w;
            u4 = x1.x; u5 = x1.y; u6 = x1.z; u7 = x1.w;
        } else {
            own = ustate_in[((size_t)w << 3) + k];
            u0 = h_lo(own.x); u1 = h_hi(own.x); u2 = h_lo(own.y); u3 = h_hi(own.y);
            u4 = h_lo(own.z); u5 = h_hi(own.z); u6 = h_lo(own.w); u7 = h_hi(own.w);
        }
        float d[12];
#pragma unroll
        for (int f = 0; f < 12; ++f) {
            const float4* lp = (f < 4 ? latent4 + f * 16 : cls4 + (f - 4) * 16) + (k << 1);
            float4 l0 = lp[0], l1 = lp[1];
            d[f] = u0*l0.x + u1*l0.y + u2*l0.z + u3*l0.w
                 + u4*l1.x + u5*l1.y + u6*l1.z + u7*l1.w;
        }
#pragma unroll
        for (int j = 0; j < 12; ++j) {
#pragma unroll
            for (int off = 1; off < 8; off <<= 1) d[j] += __shfl_xor(d[j], off, 8);
        }
        float m4 = fmaxf(fmaxf(d[0], d[1]), fmaxf(d[2], d[3]));
        float e40 = expf(d[0] - m4), e41 = expf(d[1] - m4);
        float e42 = expf(d[2] - m4), e43 = expf(d[3] - m4);
        float r4 = 1.0f / (e40 + e41 + e42 + e43);
        float af0 = e40 * r4, af1 = e41 * r4, af2 = e42 * r4, af3 = e43 * r4;
        float m8 = d[4];
#pragma unroll
        for (int c = 1; c < 8; ++c) m8 = fmaxf(m8, d[4 + c]);
        float e8[8]; float s8 = 0.f;
#pragma unroll
        for (int c = 0; c < 8; ++c) { e8[c] = expf(d[4 + c] - m8); s8 += e8[c]; }
        float a8e = e8[0];
#pragma unroll
        for (int c = 1; c < 8; ++c) if (k == c) a8e = e8[c];
        float a8v = a8e / s8;                 // lane k holds att8[w][k]

        // ---- gather loop ----
        int2 ec[8];
#pragma unroll
        for (int q = 0; q < 8; ++q) ec[q] = pv[q];            // pad-safe overread
        for (int bse = 0; bse < nE; bse += 8) {
            int c = nE - bse;
            int2 en[8];
#pragma unroll
            for (int q = 0; q < 8; ++q) en[q] = pv[bse + 8 + q];  // prefetch next
            uint4 ev[8]; float wg[8];
#pragma unroll
            for (int q = 0; q < 8; ++q) {
                int p = ec[q].x;
                int pe = (q < c) ? p : 0;                     // safe row for invalid
                ev[q] = etab[(((size_t)(pe >> 3)) << 3) + k];
                float wgt = __int_as_float(ec[q].y) * (1.0f + __shfl(a8v, p & 7, 8));
                wg[q] = (q < c) ? wgt : 0.0f;                 // kill garbage (incl. NaN)
            }
#pragma unroll
            for (int q = 0; q < 8; ++q) {
                a0 = fmaf(h_lo(ev[q].x), wg[q], a0);
                a1 = fmaf(h_hi(ev[q].x), wg[q], a1);
                a2 = fmaf(h_lo(ev[q].y), wg[q], a2);
                a3 = fmaf(h_hi(ev[q].y), wg[q], a3);
                a4 = fmaf(h_lo(ev[q].z), wg[q], a4);
                a5 = fmaf(h_hi(ev[q].z), wg[q], a5);
                a6 = fmaf(h_lo(ev[q].w), wg[q], a6);
                a7 = fmaf(h_hi(ev[q].w), wg[q], a7);
            }
#pragma unroll
            for (int q = 0; q < 8; ++q) ec[q] = en[q];
        }
#pragma unroll
        for (int f = 0; f < 4; ++f) {
            float a = (f == 0) ? af0 : (f == 1) ? af1 : (f == 2) ? af2 : af3;
            const float4* dd = dw4 + f * 16 + (k << 1);
            float4 d0 = dd[0], d1 = dd[1];
            a0 = fmaf(a, d0.x, a0); a1 = fmaf(a, d0.y, a1);
            a2 = fmaf(a, d0.z, a2); a3 = fmaf(a, d0.w, a3);
            a4 = fmaf(a, d1.x, a4); a5 = fmaf(a, d1.y, a5);
            a6 = fmaf(a, d1.z, a6); a7 = fmaf(a, d1.w, a7);
        }
        float ss = a0*a0 + a1*a1 + a2*a2 + a3*a3 + a4*a4 + a5*a5 + a6*a6 + a7*a7;
#pragma unroll
        for (int m = 1; m < 8; m <<= 1) ss += __shfl_xor(ss, m, 8);
        float s = 1.0f / fmaxf(sqrtf(ss), 1e-12f);
        float v0 = a0*s, v1 = a1*s, v2 = a2*s, v3 = a3*s;
        float v4 = a4*s, v5 = a5*s, v6 = a6*s, v7 = a7*s;
        if (MODE == 0) {
            stateU_out[((size_t)w << 3) + k] =
                make_uint4(packh(v0, v1), packh(v2, v3), packh(v4, v5), packh(v6, v7));
        } else {
            size_t b = ((size_t)w << 4) + (k << 1);
            float4 b0 = usrbase[b], b1 = usrbase[b + 1];
            float4 o0 = make_float4(b0.x + h_lo(own.x) + v0, b0.y + h_hi(own.x) + v1,
                                    b0.z + h_lo(own.y) + v2, b0.w + h_hi(own.y) + v3);
            float4 o1 = make_float4(b1.x + h_lo(own.z) + v4, b1.y + h_hi(own.z) + v5,
                                    b1.z + h_lo(own.w) + v6, b1.w + h_hi(own.w) + v7);
            outU[b] = o0; outU[b + 1] = o1;
        }
    }
}

// ---------------------------------------------------------------------------
extern "C" void kernel_launch(void* const* d_in, const int* in_sizes, int n_in,
                              void* d_out, int out_size, void* d_ws, size_t ws_size,
                              hipStream_t stream) {
    const float* user_emb   = (const float*)d_in[0];
    const float* entity_emb = (const float*)d_in[1];
    const float* cls_emb    = (const float*)d_in[2];
    const float* latent_emb = (const float*)d_in[3];
    const float* rel_emb    = (const float*)d_in[4];
    const float* disen      = (const float*)d_in[5];
    const int*   edge_index = (const int*)d_in[6];
    const int*   edge_type  = (const int*)d_in[7];
    const int*   inter_user = (const int*)d_in[8];
    const int*   inter_item = (const int*)d_in[9];
    const float* inter_val  = (const float*)d_in[10];
    const int*   inter_cls  = (const int*)d_in[11];

    float* out      = (float*)d_out;
    float* out_ent  = out;
    float* out_user = out + (size_t)N_ENT * D;
    float* out_loss = out + (size_t)N_ENT * D + (size_t)N_USERS * D;

    // workspace layout (256-B aligned blocks)
    char* w = (char*)d_ws;
    auto alloc = [&](size_t bytes) -> char* {
        char* p = w;
        w += (bytes + 255) & ~(size_t)255;
        return p;
    };
    uint*  ebuf0 = (uint*)alloc((size_t)E_ROWS * 32 * 4);        // f16 entity table (+zero row)
    uint*  eA    = (uint*)alloc((size_t)E_ROWS * 32 * 4);        // hop-0 entity state (+zero row)
    uint*  uA    = (uint*)alloc((size_t)N_USERS * 32 * 4);       // hop-0 user state
    int*   epay  = (int*)alloc((size_t)(N_EDGES + 32) * 4);      // +pad (overrun reads)
    int2*  ipv   = (int2*)alloc((size_t)(N_INTER + 32) * 8);     // +pad
    int*   eoff  = (int*)alloc((size_t)(N_ENT + 4) * 4);
    int*   uoff  = (int*)alloc((size_t)(N_USERS + 4) * 4);
    int*   GE    = (int*)alloc((size_t)NB_E * NBKT_E * 4);
    int*   RE    = (int*)alloc((size_t)NB_E * (NBKT_E + 1) * 4);
    int*   GU    = (int*)alloc((size_t)NB_U * NBKT_U * 4);
    int*   RU    = (int*)alloc((size_t)NB_U * (NBKT_U + 1) * 4);
    int*   totE  = (int*)alloc((size_t)NBKT_E * 4);
    int*   totU  = (int*)alloc((size_t)NBKT_U * 4);
    int*   baseE = (int*)alloc((size_t)(NBKT_E + 1) * 4);
    int*   baseU = (int*)alloc((size_t)(NBKT_U + 1) * 4);
    uint4* relh  = (uint4*)alloc((size_t)N_REL * 8 * 16);        // f16 rel table (2 KB)
    float* dw    = (float*)alloc((size_t)N_FAC * D * 4);
    int*   dctr  = (int*)alloc(256);                             // election counter

    // staging buffers alias hop-state buffers (consumed by k_final before hops write)
    uint2* stagE = (uint2*)eA;   // NB_E*CHUNK*8 = 8.03 MB <= 12.8 MB
    uint2* stagU = (uint2*)uA;   // NB_U*CHUNK*8 = 4.03 MB <=  6.4 MB

    const int* head = edge_index;
    const int* tail = edge_index + N_EDGES;

    // 1: convert + dw/loss/rel-table + counter zero
    k_cvt_dw<<<2048, 256, 0, stream>>>((const float2*)entity_emb, ebuf0,
                                       N_ENT * 32, E_ROWS * 32,
                                       disen, rel_emb, dw, out_loss, relh, dctr);
    // 2-4: CSR build
    k_sort <<<NB_E + NB_U, 256, 0, stream>>>(head, tail, edge_type,
                                             inter_user, inter_item, inter_cls, inter_val,
                                             stagE, GE, RE, stagU, GU, RU);
    k_bscan<<<NBKT_E + NBKT_U, 64, 0, stream>>>(GE, totE, GU, totU,
                                                baseE, baseU, eoff, uoff, dctr);
    k_final<<<NBKT_E + NBKT_U, 256, 0, stream>>>(stagE, GE, RE, baseE,
                                                 stagU, GU, RU, baseU,
                                                 eoff, uoff, epay, ipv);

    const int hop_blocks = ((E_ROWS + N_USERS) * 8 + 255) / 256;

    // 5: hop 0 (fused user att from f32 user_emb; writes packed states)
    k_hop<0><<<hop_blocks, 256, 0, stream>>>((const uint4*)ebuf0, nullptr,
                                             (const float4*)user_emb, nullptr,
                                             relh, eoff, epay, uoff, ipv,
                                             (const float4*)latent_emb,
                                             (const float4*)cls_emb,
                                             (const float4*)dw,
                                             (uint4*)eA, (uint4*)uA,
                                             nullptr, nullptr);

    // 6: hop 1 (fused user att from uA; out = base + own_state + v)
    k_hop<1><<<hop_blocks, 256, 0, stream>>>((const uint4*)eA,
                                             (const float4*)entity_emb,
                                             (const float4*)user_emb,
                                             (const uint4*)uA,
                                             relh, eoff, epay, uoff, ipv,
                                             (const float4*)latent_emb,
                                             (const float4*)cls_emb,
                                             (const float4*)dw,
                                             nullptr, nullptr,
                                             (float4*)out_ent, (float4*)out_user);
}

// Round 5
// 132.164 us; speedup vs baseline: 1.5836x; 1.5836x over previous
//
#include <hip/hip_runtime.h>
#include <math.h>

typedef unsigned int uint;

constexpr int N_USERS  = 50000;
constexpr int N_ENT    = 100000;
constexpr int D        = 64;
constexpr int N_FAC    = 4;
constexpr int N_CLS    = 8;
constexpr int N_REL    = 16;
constexpr int N_EDGES  = 1000000;
constexpr int N_INTER  = 500000;

// bucket-sort geometry
constexpr int BSH      = 7;                              // 128 segments per bucket
constexpr int SPB      = 1 << BSH;                       // 128
constexpr int NBKT_E   = (N_ENT   + SPB - 1) / SPB;      // 782
constexpr int NBKT_U   = (N_USERS + SPB - 1) / SPB;      // 391
constexpr int CHUNK    = 4096;                           // edges per sort block
constexpr int NB_E     = (N_EDGES + CHUNK - 1) / CHUNK;  // 245
constexpr int NB_U     = (N_INTER + CHUNK - 1) / CHUNK;  // 123
constexpr int EBUF_CAP = 3072;                           // max bucket size (mean ~1280)

constexpr int E_ROWS   = N_ENT + 1;                      // incl. zero row

static_assert(NB_E <= 256 && NB_U <= 256, "k_final local scan assumes NB <= 256");

// ---- f16x2 helpers (packed two f16 in one uint) ----
typedef _Float16 h2_t __attribute__((ext_vector_type(2)));
union U32H2 { uint u; h2_t h; };

__device__ inline float h_lo(uint v) { U32H2 x; x.u = v; return (float)x.h.x; }
__device__ inline float h_hi(uint v) { U32H2 x; x.u = v; return (float)x.h.y; }
__device__ inline uint packh(float a, float b) {
    auto r = __builtin_amdgcn_cvt_pkrtz(a, b);   // v_cvt_pkrtz_f16_f32, single inst
    union { decltype(r) h; uint u; } x;
    x.h = r;
    return x.u;
}

__device__ inline int wscan64_incl(int x, int lane) {
#pragma unroll
    for (int off = 1; off < 64; off <<= 1) {
        int v = __shfl_up(x, off, 64);
        if (lane >= off) x += v;
    }
    return x;
}

// 256-thread block scan (inclusive) of per-thread values
__device__ inline int block_scan_incl(int x, int* wsum) {
    int lane = threadIdx.x & 63, wv = threadIdx.x >> 6;
#pragma unroll
    for (int off = 1; off < 64; off <<= 1) {
        int v = __shfl_up(x, off, 64);
        if (lane >= off) x += v;
    }
    if (lane == 63) wsum[wv] = x;
    __syncthreads();
    if (wv == 0 && lane < 16) {
        int s = wsum[lane];
#pragma unroll
        for (int off = 1; off < 16; off <<= 1) {
            int v = __shfl_up(s, off, 64);
            if (lane >= off) s += v;
        }
        wsum[lane] = s;
    }
    __syncthreads();
    if (wv > 0) x += wsum[wv - 1];
    return x;
}

// ---- fused: f32 -> f16 entity table convert (blocks 0..N-2)
//      + dw/loss/rel-f16-table + tot[] zeroing (last block) ----
__global__ void k_cvt_dw(const float2* __restrict__ in, uint* __restrict__ out,
                         int n_src, int n_out,
                         const float* __restrict__ datt,
                         const float* __restrict__ rel,
                         float* __restrict__ dw,
                         float* __restrict__ loss_out,
                         uint4* __restrict__ relh4,
                         int* __restrict__ totE,
                         int* __restrict__ totU) {
    __shared__ float p[N_FAC][N_REL];
    __shared__ float nrm[N_FAC];
    __shared__ float sc[N_FAC][N_FAC];
    int t = threadIdx.x;
    if (blockIdx.x == gridDim.x - 1) {
        for (int s = t; s < NBKT_E; s += 256) totE[s] = 0;
        for (int s = t; s < NBKT_U; s += 256) totU[s] = 0;
        // f16 rel table (128 slots)
        for (int s = t; s < N_REL * 8; s += 256) {
            int r = s >> 3, kk = s & 7;
            const float* rp = rel + r * 64 + kk * 8;
            relh4[s] = make_uint4(packh(rp[0], rp[1]), packh(rp[2], rp[3]),
                                  packh(rp[4], rp[5]), packh(rp[6], rp[7]));
        }
        if (t < N_FAC) {
            float m = -1e30f;
            for (int r = 0; r < N_REL; ++r) m = fmaxf(m, datt[t * N_REL + r]);
            float tmp[N_REL]; float s = 0.f;
            for (int r = 0; r < N_REL; ++r) { tmp[r] = expf(datt[t * N_REL + r] - m); s += tmp[r]; }
            for (int r = 0; r < N_REL; ++r) p[t][r] = tmp[r] / s;
            float ss = 0.f;
            for (int r = 0; r < N_REL; ++r) { float v = datt[t * N_REL + r]; ss += v * v; }
            nrm[t] = fmaxf(sqrtf(ss), 1e-12f);
        }
        __syncthreads();
        if (t < D) {
            for (int f = 0; f < N_FAC; ++f) {
                float acc = 0.f;
                for (int r = 0; r < N_REL; ++r) acc += p[f][r] * rel[r * D + t];
                dw[f * D + t] = acc;
            }
        }
        if (t < N_FAC * N_FAC) {
            int i = t >> 2, j = t & 3;
            float s = 0.f;
            for (int r = 0; r < N_REL; ++r) s += datt[i * N_REL + r] * datt[j * N_REL + r];
            s /= nrm[i] * nrm[j];
            sc[i][j] = expf(s * 5.0f);   // exp(s / 0.2)
        }
        __syncthreads();
        if (t == 0) {
            float loss = 0.f;
            for (int i = 0; i < N_FAC; ++i) {
                float rowsum = 0.f;
                for (int j = 0; j < N_FAC; ++j) rowsum += sc[i][j];
                loss += logf(sc[i][i] / rowsum);
            }
            *loss_out = -loss;
        }
        return;
    }
    int nb = gridDim.x - 1;
    for (int i = blockIdx.x * 256 + t; i < n_out; i += nb * 256) {
        if (i < n_src) {
            float2 v = in[i];
            out[i] = packh(v.x, v.y);
        } else {
            out[i] = 0u;
        }
    }
}

// ---- P1: per-block LDS counting sort -> linear staging (all writes coalesced).
// Also atomically accumulates per-bucket totals (no separate scan kernel). ----
__global__ void k_sort(const int* __restrict__ headE, const int* __restrict__ tailE,
                       const int* __restrict__ etype,
                       const int* __restrict__ iu, const int* __restrict__ ii,
                       const int* __restrict__ icls, const float* __restrict__ ival,
                       uint2* __restrict__ stagE, int* __restrict__ GE, int* __restrict__ RE,
                       uint2* __restrict__ stagU, int* __restrict__ GU, int* __restrict__ RU,
                       int* __restrict__ totE, int* __restrict__ totU) {
    __shared__ int hist[NBKT_E];
    __shared__ int soff[NBKT_E + 1];
    __shared__ int cursor[NBKT_E];
    __shared__ int wsum[16];
    __shared__ uint2 sorted[CHUNK];
    int bid = blockIdx.x;
    bool isE = bid < NB_E;
    int blk  = isE ? bid : bid - NB_E;
    int n    = isE ? N_EDGES : N_INTER;
    int nbkt = isE ? NBKT_E : NBKT_U;
    int base = blk * CHUNK;
    int end  = min(base + CHUNK, n);
    int cblk = end - base;

    for (int b = threadIdx.x; b < nbkt; b += 256) hist[b] = 0;
    __syncthreads();

    // load 16 edges/thread into registers (static indexing), histogram buckets
    uint2 ent[16]; int ebk[16];
#pragma unroll
    for (int j = 0; j < 16; ++j) {
        int i = base + threadIdx.x + j * 256;
        ebk[j] = -1;
        if (i < end) {
            uint x, y; int b;
            if (isE) {
                int h = headE[i];
                x = (uint)h; y = (uint)((tailE[i] << 4) | etype[i]); b = h >> BSH;
            } else {
                int u = iu[i];
                x = (uint)((u << 15) | ii[i]);
                y = (__float_as_uint(ival[i]) & ~7u) | (uint)icls[i];
                b = u >> BSH;
            }
            ent[j] = make_uint2(x, y); ebk[j] = b;
            atomicAdd(&hist[b], 1);
        }
    }
    __syncthreads();

    // block scan over nbkt bins: thread t owns bins [t*4, t*4+4)
    int b0 = threadIdx.x * 4;
    int lsum[4]; int mysum = 0;
#pragma unroll
    for (int j = 0; j < 4; ++j) {
        int b = b0 + j;
        int v = (b < nbkt) ? hist[b] : 0;
        lsum[j] = mysum; mysum += v;
    }
    int excl = block_scan_incl(mysum, wsum) - mysum;
#pragma unroll
    for (int j = 0; j < 4; ++j) {
        int b = b0 + j;
        if (b < nbkt) soff[b] = excl + lsum[j];
    }
    if (threadIdx.x == 0) soff[nbkt] = cblk;
    __syncthreads();
    for (int b = threadIdx.x; b < nbkt; b += 256) cursor[b] = soff[b];
    __syncthreads();

    // LDS scatter into sorted order
#pragma unroll
    for (int j = 0; j < 16; ++j) {
        if (ebk[j] >= 0) {
            int p = atomicAdd(&cursor[ebk[j]], 1);
            sorted[p] = ent[j];
        }
    }
    __syncthreads();

    // coalesced writes: staging chunk + hist row + rowscan row + bucket totals
    uint2* stag = isE ? stagE : stagU;
    int* G = isE ? GE : GU;
    int* R = isE ? RE : RU;
    int* tot = isE ? totE : totU;
    for (int i = threadIdx.x; i < cblk; i += 256) stag[blk * CHUNK + i] = sorted[i];
    for (int b = threadIdx.x; b < nbkt; b += 256) {
        G[blk * nbkt + b] = hist[b];
        if (hist[b]) atomicAdd(&tot[b], hist[b]);
    }
    for (int b = threadIdx.x; b <= nbkt; b += 256) R[blk * (nbkt + 1) + b] = soff[b];
}

// ---- P2: scan bucket totals -> bucket bases (wave0: E, wave1: U) ----
__device__ inline void scan_tot(const int* __restrict__ tot, int* __restrict__ base,
                                int nbkt, int l, int* __restrict__ off_last, int nseg) {
    int carry = 0;
    for (int b = 0; b < nbkt; b += 64) {
        int x = (b + l < nbkt) ? tot[b + l] : 0;
        int incl = wscan64_incl(x, l);
        if (b + l < nbkt) base[b + l] = carry + incl - x;
        carry += __shfl(incl, 63, 64);
    }
    if (l == 0) {
        base[nbkt] = carry;
        off_last[nseg] = carry;
        off_last[nseg + 1] = carry;   // zero-row segment (entity) / unused (user)
    }
}

__global__ void k_base(const int* __restrict__ totE, int* __restrict__ baseE,
                       const int* __restrict__ totU, int* __restrict__ baseU,
                       int* __restrict__ eoff, int* __restrict__ uoff) {
    int t = threadIdx.x;
    if (t < 64) scan_tot(totE, baseE, NBKT_E, t, eoff, N_ENT);
    else        scan_tot(totU, baseU, NBKT_U, t - 64, uoff, N_USERS);
}

// ---- P3: per-bucket finalize. Locally scans this bucket's raw count column
// (NB <= 256 -> one block-scan) to get per-chunk dst offsets (replaces the
// old global bscanA pass), then gathers runs, seg-sorts, places. ----
__global__ void k_final(const uint2* __restrict__ stagE, const int* __restrict__ GE,
                        const int* __restrict__ RE, const int* __restrict__ baseE,
                        const uint2* __restrict__ stagU, const int* __restrict__ GU,
                        const int* __restrict__ RU, const int* __restrict__ baseU,
                        int* __restrict__ eoff, int* __restrict__ uoff,
                        int* __restrict__ epay, int2* __restrict__ ipv) {
    __shared__ uint2 ebuf[EBUF_CAP];
    __shared__ int cnt[SPB], soff[SPB], cur[SPB];
    __shared__ int wsum[16];
    int bid = blockIdx.x;
    bool isE = bid < NBKT_E;
    int bkt = bid < NBKT_E ? bid : bid - NBKT_E;
    const uint2* stag = isE ? stagE : stagU;
    const int* G  = isE ? GE : GU;
    const int* R  = isE ? RE : RU;
    const int* bb = isE ? baseE : baseU;
    int* off      = isE ? eoff : uoff;
    int NB   = isE ? NB_E : NB_U;
    int nbkt = isE ? NBKT_E : NBKT_U;
    int nseg = isE ? N_ENT : N_USERS;
    int r0 = bb[bkt], r1 = bb[bkt + 1];
    int bsz = r1 - r0;
    int t = threadIdx.x;
    // local scan of this bucket's per-chunk counts -> dst offsets (blk == t)
    int myc = (t < NB) ? G[t * nbkt + bkt] : 0;
    int mydst = block_scan_incl(myc, wsum) - myc;
    if (t < SPB) cnt[t] = 0;
    // phase A: gather each chunk's run into LDS at its bucket-relative offset
    if (t < NB) {
        int rs  = R[t * (nbkt + 1) + bkt];
        int re  = R[t * (nbkt + 1) + bkt + 1];
        for (int j = rs; j < re; ++j) {
            int d = mydst + (j - rs);
            if (d < EBUF_CAP) ebuf[d] = stag[t * CHUNK + j];
        }
    }
    __syncthreads();
    // phase B: histogram over 128 segments
    for (int i = t; i < bsz; i += 256) {
        uint2 e = ebuf[i];
        int s = (int)(isE ? e.x : (e.x >> 15)) & (SPB - 1);
        atomicAdd(&cnt[s], 1);
    }
    __syncthreads();
    // phase C: scan 128 segments
    if (t < 64) {
        int a0 = cnt[2 * t], a1 = cnt[2 * t + 1];
        int incl = wscan64_incl(a0 + a1, t);
        int excl = incl - (a0 + a1);
        soff[2 * t] = excl;
        soff[2 * t + 1] = excl + a0;
    }
    __syncthreads();
    if (t < SPB) {
        cur[t] = soff[t];
        int seg = bkt * SPB + t;
        if (seg < nseg) off[seg] = r0 + soff[t];
    }
    __syncthreads();
    // phase D: scatter to final CSR (writes land in this bucket's ~10 KB window)
    for (int i = t; i < bsz; i += 256) {
        uint2 e = ebuf[i];
        int s = (int)(isE ? e.x : (e.x >> 15)) & (SPB - 1);
        int pos = r0 + atomicAdd(&cur[s], 1);
        if (isE) {
            epay[pos] = (int)e.y;
        } else {
            int item = (int)(e.x & 0x7FFF), cls = (int)(e.y & 7u);
            ipv[pos] = make_int2((item << 3) | cls, (int)(e.y & ~7u));
        }
    }
}

// ---- merged hop with FUSED user attention.
// rows [0, N_ENT] = entity (incl. zero row N_ENT), rest = user.
// 8 lanes per row, 8 dims per lane (uint4 f16x8 gathers).
// Depth-8 register gather pipeline; f16 rel table (one uint4 load/edge).
// User branch computes its own att4/att8 in-register (latent/cls L1-resident,
// 8-lane butterfly reduce) - no separate k_user_att dispatches.
// MODE 0: att from f32 user_emb; write packed states.
// MODE 1: att from f16 uA state; out = base + own_state + v.
template<int MODE>
__global__ __launch_bounds__(256)
void k_hop(const uint4* __restrict__ etab,      // gather table (f16), E_ROWS rows
           const float4* __restrict__ entbase,  // entity_emb (MODE 1)
           const float4* __restrict__ usrbase,  // user_emb f32 (att MODE 0; base MODE 1)
           const uint4* __restrict__ ustate_in, // uA f16 (att + own, MODE 1)
           const uint4* __restrict__ relh4,     // f16 rel table [16][8]
           const int* __restrict__ eoff,
           const int* __restrict__ epay,
           const int* __restrict__ uoff,
           const int2* __restrict__ ipv,
           const float4* __restrict__ latent4,  // f32 [4][16]
           const float4* __restrict__ cls4,     // f32 [8][16]
           const float4* __restrict__ dw4,      // f32 [4][16]
           uint4* __restrict__ stateE_out,
           uint4* __restrict__ stateU_out,
           float4* __restrict__ outE,
           float4* __restrict__ outU) {
    int gid = blockIdx.x * 256 + threadIdx.x;
    int gw = gid >> 3;
    int k = threadIdx.x & 7;
    if (gw >= E_ROWS + N_USERS) return;
    bool isEnt = gw < E_ROWS;
    float a0 = 0.f, a1 = 0.f, a2 = 0.f, a3 = 0.f;
    float a4 = 0.f, a5 = 0.f, a6 = 0.f, a7 = 0.f;

    if (isEnt) {
        int w = gw;
        int beg = eoff[w], end = eoff[w + 1];
        int nE = end - beg;
        const int* pp = epay + beg;
        int pc[8];
#pragma unroll
        for (int q = 0; q < 8; ++q) pc[q] = pp[q];            // pad-safe overread
        for (int bse = 0; bse < nE; bse += 8) {
            int c = nE - bse;
            int pn[8];
#pragma unroll
            for (int q = 0; q < 8; ++q) pn[q] = pp[bse + 8 + q];  // prefetch next
            uint4 ev[8], rl[8];
#pragma unroll
            for (int q = 0; q < 8; ++q) {
                int p = (q < c) ? pc[q] : (N_ENT << 4);       // invalid -> zero row
                ev[q] = etab[(((size_t)(p >> 4)) << 3) + k];
                rl[q] = relh4[((p & 15) << 3) + k];
            }
#pragma unroll
            for (int q = 0; q < 8; ++q) {
                a0 = fmaf(h_lo(ev[q].x), h_lo(rl[q].x), a0);
                a1 = fmaf(h_hi(ev[q].x), h_hi(rl[q].x), a1);
                a2 = fmaf(h_lo(ev[q].y), h_lo(rl[q].y), a2);
                a3 = fmaf(h_hi(ev[q].y), h_hi(rl[q].y), a3);
                a4 = fmaf(h_lo(ev[q].z), h_lo(rl[q].z), a4);
                a5 = fmaf(h_hi(ev[q].z), h_hi(rl[q].z), a5);
                a6 = fmaf(h_lo(ev[q].w), h_lo(rl[q].w), a6);
                a7 = fmaf(h_hi(ev[q].w), h_hi(rl[q].w), a7);
            }
#pragma unroll
            for (int q = 0; q < 8; ++q) pc[q] = pn[q];
        }
        float ss = a0*a0 + a1*a1 + a2*a2 + a3*a3 + a4*a4 + a5*a5 + a6*a6 + a7*a7;
#pragma unroll
        for (int m = 1; m < 8; m <<= 1) ss += __shfl_xor(ss, m, 8);
        float s = 1.0f / fmaxf(sqrtf(ss), 1e-12f);
        float v0 = a0*s, v1 = a1*s, v2 = a2*s, v3 = a3*s;
        float v4 = a4*s, v5 = a5*s, v6 = a6*s, v7 = a7*s;
        if (MODE == 0) {
            stateE_out[((size_t)w << 3) + k] =
                make_uint4(packh(v0, v1), packh(v2, v3), packh(v4, v5), packh(v6, v7));
        } else if (w < N_ENT) {
            size_t b = ((size_t)w << 4) + (k << 1);
            float4 b0 = entbase[b], b1 = entbase[b + 1];
            uint4 own = etab[((size_t)w << 3) + k];
            float4 o0 = make_float4(b0.x + h_lo(own.x) + v0, b0.y + h_hi(own.x) + v1,
                                    b0.z + h_lo(own.y) + v2, b0.w + h_hi(own.y) + v3);
            float4 o1 = make_float4(b1.x + h_lo(own.z) + v4, b1.y + h_hi(own.z) + v5,
                                    b1.z + h_lo(own.w) + v6, b1.w + h_hi(own.w) + v7);
            outE[b] = o0; outE[b + 1] = o1;
        }
    } else {
        int w = gw - E_ROWS;
        int beg = uoff[w], end = uoff[w + 1];
        int nE = end - beg;
        const int2* pv = ipv + beg;

        // ---- fused attention: own row dims 8k..8k+7 ----
        float u0, u1, u2, u3, u4, u5, u6, u7;
        uint4 own;
        if (MODE == 0) {
            size_t bb = ((size_t)w << 4) + (k << 1);
            float4 x0 = usrbase[bb], x1 = usrbase[bb + 1];
            u0 = x0.x; u1 = x0.y; u2 = x0.z; u3 = x0.w;
            u4 = x1.x; u5 = x1.y; u6 = x1.z; u7 = x1.w;
        } else {
            own = ustate_in[((size_t)w << 3) + k];
            u0 = h_lo(own.x); u1 = h_hi(own.x); u2 = h_lo(own.y); u3 = h_hi(own.y);
            u4 = h_lo(own.z); u5 = h_hi(own.z); u6 = h_lo(own.w); u7 = h_hi(own.w);
        }
        float d[12];
#pragma unroll
        for (int f = 0; f < 12; ++f) {
            const float4* lp = (f < 4 ? latent4 + f * 16 : cls4 + (f - 4) * 16) + (k << 1);
            float4 l0 = lp[0], l1 = lp[1];
            d[f] = u0*l0.x + u1*l0.y + u2*l0.z + u3*l0.w
                 + u4*l1.x + u5*l1.y + u6*l1.z + u7*l1.w;
        }
#pragma unroll
        for (int j = 0; j < 12; ++j) {
#pragma unroll
            for (int off = 1; off < 8; off <<= 1) d[j] += __shfl_xor(d[j], off, 8);
        }
        float m4 = fmaxf(fmaxf(d[0], d[1]), fmaxf(d[2], d[3]));
        float e40 = expf(d[0] - m4), e41 = expf(d[1] - m4);
        float e42 = expf(d[2] - m4), e43 = expf(d[3] - m4);
        float r4 = 1.0f / (e40 + e41 + e42 + e43);
        float af0 = e40 * r4, af1 = e41 * r4, af2 = e42 * r4, af3 = e43 * r4;
        float m8 = d[4];
#pragma unroll
        for (int c = 1; c < 8; ++c) m8 = fmaxf(m8, d[4 + c]);
        float e8[8]; float s8 = 0.f;
#pragma unroll
        for (int c = 0; c < 8; ++c) { e8[c] = expf(d[4 + c] - m8); s8 += e8[c]; }
        float a8e = e8[0];
#pragma unroll
        for (int c = 1; c < 8; ++c) if (k == c) a8e = e8[c];
        float a8v = a8e / s8;                 // lane k holds att8[w][k]

        // ---- gather loop ----
        int2 ec[8];
#pragma unroll
        for (int q = 0; q < 8; ++q) ec[q] = pv[q];            // pad-safe overread
        for (int bse = 0; bse < nE; bse += 8) {
            int c = nE - bse;
            int2 en[8];
#pragma unroll
            for (int q = 0; q < 8; ++q) en[q] = pv[bse + 8 + q];  // prefetch next
            uint4 ev[8]; float wg[8];
#pragma unroll
            for (int q = 0; q < 8; ++q) {
                int p = ec[q].x;
                int pe = (q < c) ? p : 0;                     // safe row for invalid
                ev[q] = etab[(((size_t)(pe >> 3)) << 3) + k];
                float wgt = __int_as_float(ec[q].y) * (1.0f + __shfl(a8v, p & 7, 8));
                wg[q] = (q < c) ? wgt : 0.0f;                 // kill garbage (incl. NaN)
            }
#pragma unroll
            for (int q = 0; q < 8; ++q) {
                a0 = fmaf(h_lo(ev[q].x), wg[q], a0);
                a1 = fmaf(h_hi(ev[q].x), wg[q], a1);
                a2 = fmaf(h_lo(ev[q].y), wg[q], a2);
                a3 = fmaf(h_hi(ev[q].y), wg[q], a3);
                a4 = fmaf(h_lo(ev[q].z), wg[q], a4);
                a5 = fmaf(h_hi(ev[q].z), wg[q], a5);
                a6 = fmaf(h_lo(ev[q].w), wg[q], a6);
                a7 = fmaf(h_hi(ev[q].w), wg[q], a7);
            }
#pragma unroll
            for (int q = 0; q < 8; ++q) ec[q] = en[q];
        }
#pragma unroll
        for (int f = 0; f < 4; ++f) {
            float a = (f == 0) ? af0 : (f == 1) ? af1 : (f == 2) ? af2 : af3;
            const float4* dd = dw4 + f * 16 + (k << 1);
            float4 d0 = dd[0], d1 = dd[1];
            a0 = fmaf(a, d0.x, a0); a1 = fmaf(a, d0.y, a1);
            a2 = fmaf(a, d0.z, a2); a3 = fmaf(a, d0.w, a3);
            a4 = fmaf(a, d1.x, a4); a5 = fmaf(a, d1.y, a5);
            a6 = fmaf(a, d1.z, a6); a7 = fmaf(a, d1.w, a7);
        }
        float ss = a0*a0 + a1*a1 + a2*a2 + a3*a3 + a4*a4 + a5*a5 + a6*a6 + a7*a7;
#pragma unroll
        for (int m = 1; m < 8; m <<= 1) ss += __shfl_xor(ss, m, 8);
        float s = 1.0f / fmaxf(sqrtf(ss), 1e-12f);
        float v0 = a0*s, v1 = a1*s, v2 = a2*s, v3 = a3*s;
        float v4 = a4*s, v5 = a5*s, v6 = a6*s, v7 = a7*s;
        if (MODE == 0) {
            stateU_out[((size_t)w << 3) + k] =
                make_uint4(packh(v0, v1), packh(v2, v3), packh(v4, v5), packh(v6, v7));
        } else {
            size_t b = ((size_t)w << 4) + (k << 1);
            float4 b0 = usrbase[b], b1 = usrbase[b + 1];
            float4 o0 = make_float4(b0.x + h_lo(own.x) + v0, b0.y + h_hi(own.x) + v1,
                                    b0.z + h_lo(own.y) + v2, b0.w + h_hi(own.y) + v3);
            float4 o1 = make_float4(b1.x + h_lo(own.z) + v4, b1.y + h_hi(own.z) + v5,
                                    b1.z + h_lo(own.w) + v6, b1.w + h_hi(own.w) + v7);
            outU[b] = o0; outU[b + 1] = o1;
        }
    }
}

// ---------------------------------------------------------------------------
extern "C" void kernel_launch(void* const* d_in, const int* in_sizes, int n_in,
                              void* d_out, int out_size, void* d_ws, size_t ws_size,
                              hipStream_t stream) {
    const float* user_emb   = (const float*)d_in[0];
    const float* entity_emb = (const float*)d_in[1];
    const float* cls_emb    = (const float*)d_in[2];
    const float* latent_emb = (const float*)d_in[3];
    const float* rel_emb    = (const float*)d_in[4];
    const float* disen      = (const float*)d_in[5];
    const int*   edge_index = (const int*)d_in[6];
    const int*   edge_type  = (const int*)d_in[7];
    const int*   inter_user = (const int*)d_in[8];
    const int*   inter_item = (const int*)d_in[9];
    const float* inter_val  = (const float*)d_in[10];
    const int*   inter_cls  = (const int*)d_in[11];

    float* out      = (float*)d_out;
    float* out_ent  = out;
    float* out_user = out + (size_t)N_ENT * D;
    float* out_loss = out + (size_t)N_ENT * D + (size_t)N_USERS * D;

    // workspace layout (256-B aligned blocks)
    char* w = (char*)d_ws;
    auto alloc = [&](size_t bytes) -> char* {
        char* p = w;
        w += (bytes + 255) & ~(size_t)255;
        return p;
    };
    uint*  ebuf0 = (uint*)alloc((size_t)E_ROWS * 32 * 4);        // f16 entity table (+zero row)
    uint*  eA    = (uint*)alloc((size_t)E_ROWS * 32 * 4);        // hop-0 entity state (+zero row)
    uint*  uA    = (uint*)alloc((size_t)N_USERS * 32 * 4);       // hop-0 user state
    int*   epay  = (int*)alloc((size_t)(N_EDGES + 32) * 4);      // +pad (overrun reads)
    int2*  ipv   = (int2*)alloc((size_t)(N_INTER + 32) * 8);     // +pad
    int*   eoff  = (int*)alloc((size_t)(N_ENT + 4) * 4);
    int*   uoff  = (int*)alloc((size_t)(N_USERS + 4) * 4);
    int*   GE    = (int*)alloc((size_t)NB_E * NBKT_E * 4);
    int*   RE    = (int*)alloc((size_t)NB_E * (NBKT_E + 1) * 4);
    int*   GU    = (int*)alloc((size_t)NB_U * NBKT_U * 4);
    int*   RU    = (int*)alloc((size_t)NB_U * (NBKT_U + 1) * 4);
    int*   totE  = (int*)alloc((size_t)NBKT_E * 4);
    int*   totU  = (int*)alloc((size_t)NBKT_U * 4);
    int*   baseE = (int*)alloc((size_t)(NBKT_E + 1) * 4);
    int*   baseU = (int*)alloc((size_t)(NBKT_U + 1) * 4);
    uint4* relh  = (uint4*)alloc((size_t)N_REL * 8 * 16);        // f16 rel table (2 KB)
    float* dw    = (float*)alloc((size_t)N_FAC * D * 4);

    // staging buffers alias hop-state buffers (consumed by k_final before hops write)
    uint2* stagE = (uint2*)eA;   // NB_E*CHUNK*8 = 8.03 MB <= 12.8 MB
    uint2* stagU = (uint2*)uA;   // NB_U*CHUNK*8 = 4.03 MB <=  6.4 MB

    const int* head = edge_index;
    const int* tail = edge_index + N_EDGES;

    // 1: convert + dw/loss/rel-table + tot zeroing
    k_cvt_dw<<<2048, 256, 0, stream>>>((const float2*)entity_emb, ebuf0,
                                       N_ENT * 32, E_ROWS * 32,
                                       disen, rel_emb, dw, out_loss, relh, totE, totU);
    // 2-4: CSR build (no global scan pass; totals via atomics, local scan in final)
    k_sort <<<NB_E + NB_U, 256, 0, stream>>>(head, tail, edge_type,
                                             inter_user, inter_item, inter_cls, inter_val,
                                             stagE, GE, RE, stagU, GU, RU, totE, totU);
    k_base <<<1, 128, 0, stream>>>(totE, baseE, totU, baseU, eoff, uoff);
    k_final<<<NBKT_E + NBKT_U, 256, 0, stream>>>(stagE, GE, RE, baseE,
                                                 stagU, GU, RU, baseU,
                                                 eoff, uoff, epay, ipv);

    const int hop_blocks = ((E_ROWS + N_USERS) * 8 + 255) / 256;

    // 5: hop 0 (fused user att from f32 user_emb; writes packed states)
    k_hop<0><<<hop_blocks, 256, 0, stream>>>((const uint4*)ebuf0, nullptr,
                                             (const float4*)user_emb, nullptr,
                                             relh, eoff, epay, uoff, ipv,
                                             (const float4*)latent_emb,
                                             (const float4*)cls_emb,
                                             (const float4*)dw,
                                             (uint4*)eA, (uint4*)uA,
                                             nullptr, nullptr);

    // 6: hop 1 (fused user att from uA; out = base + own_state + v)
    k_hop<1><<<hop_blocks, 256, 0, stream>>>((const uint4*)eA,
                                             (const float4*)entity_emb,
                                             (const float4*)user_emb,
                                             (const uint4*)uA,
                                             relh, eoff, epay, uoff, ipv,
                                             (const float4*)latent_emb,
                                             (const float4*)cls_emb,
                                             (const float4*)dw,
                                             nullptr, nullptr,
                                             (float4*)out_ent, (float4*)out_user);
}